// Round 4
// baseline (303.316 us; speedup 1.0000x reference)
//
#include <hip/hip_runtime.h>

typedef float f4 __attribute__((ext_vector_type(4)));

#define NEG 0.2f
constexpr int B_ = 8, N_ = 1024;

// ---------------------------------------------------------------------------
// Kernel 1: h = x @ W^T (M=8192,N=128,K=128) + src/dst projections. Unchanged.
// ---------------------------------------------------------------------------
__global__ __launch_bounds__(256) void gat_h_kernel(
    const float* __restrict__ x, const float* __restrict__ Ww,
    const float* __restrict__ attn,
    float* __restrict__ hfeat, float* __restrict__ srcv, float* __restrict__ dstv)
{
    __shared__ float Wl[128 * 128];
    const int tid = threadIdx.x;
    const int row0 = blockIdx.x * 16;

    #pragma unroll
    for (int k = 0; k < 16; ++k) {
        int f = tid + k * 256;
        int o = f >> 5, ib = f & 31;
        float4 w = *(const float4*)(Ww + o * 128 + ib * 4);
        *(float4*)&Wl[o * 128 + ((ib ^ ((o >> 2) & 7)) << 2)] = w;
    }
    __syncthreads();

    const int colg = tid & 31;
    const int rg   = tid >> 5;
    const int swz  = colg & 7;
    float acc[2][4] = {};
    const float* xr = x + (size_t)(row0 + rg * 2) * 128;

    #pragma unroll 8
    for (int is = 0; is < 32; ++is) {
        float4 x0 = *(const float4*)(xr + is * 4);
        float4 x1 = *(const float4*)(xr + 128 + is * 4);
        #pragma unroll
        for (int cc = 0; cc < 4; ++cc) {
            float4 wv = *(const float4*)&Wl[(colg * 4 + cc) * 128 + ((is ^ swz) << 2)];
            acc[0][cc] = fmaf(x0.x, wv.x, acc[0][cc]);
            acc[0][cc] = fmaf(x0.y, wv.y, acc[0][cc]);
            acc[0][cc] = fmaf(x0.z, wv.z, acc[0][cc]);
            acc[0][cc] = fmaf(x0.w, wv.w, acc[0][cc]);
            acc[1][cc] = fmaf(x1.x, wv.x, acc[1][cc]);
            acc[1][cc] = fmaf(x1.y, wv.y, acc[1][cc]);
            acc[1][cc] = fmaf(x1.z, wv.z, acc[1][cc]);
            acc[1][cc] = fmaf(x1.w, wv.w, acc[1][cc]);
        }
    }
    #pragma unroll
    for (int r = 0; r < 2; ++r) {
        float4 hv = make_float4(acc[r][0], acc[r][1], acc[r][2], acc[r][3]);
        *(float4*)(hfeat + (size_t)(row0 + rg * 2 + r) * 128 + colg * 4) = hv;
    }
    const int hh = colg >> 3;
    float ps[2] = {0.f, 0.f}, pd[2] = {0.f, 0.f};
    #pragma unroll
    for (int cc = 0; cc < 4; ++cc) {
        int fi = (colg & 7) * 4 + cc;
        float as = attn[hh * 65 + fi];
        float ad = attn[hh * 65 + 32 + fi];
        ps[0] = fmaf(acc[0][cc], as, ps[0]); ps[1] = fmaf(acc[1][cc], as, ps[1]);
        pd[0] = fmaf(acc[0][cc], ad, pd[0]); pd[1] = fmaf(acc[1][cc], ad, pd[1]);
    }
    #pragma unroll
    for (int m = 1; m <= 4; m <<= 1) {
        ps[0] += __shfl_xor(ps[0], m); ps[1] += __shfl_xor(ps[1], m);
        pd[0] += __shfl_xor(pd[0], m); pd[1] += __shfl_xor(pd[1], m);
    }
    if ((tid & 7) == 0) {
        #pragma unroll
        for (int r = 0; r < 2; ++r) {
            srcv[(size_t)(row0 + rg * 2 + r) * 4 + hh] = ps[r];
            dstv[(size_t)(row0 + rg * 2 + r) * 4 + hh] = pd[r];
        }
    }
}

// ---------------------------------------------------------------------------
// Kernel 2: 1024 blocks (b=bid&7 -> XCD-local) x 512 thr, TI=8 rows.
// 4 blk/CU x 8 waves = 32 waves/CU. No h staging (L2-hot direct reads).
// Pass A: 1 row/wave sum-of-exp. Per 64-j tile:
//   phase1 (1 task/thr): alpha -> al_l[h][jj][12] + nt global store
//   phase2: prefetch next adj; outer-product PV acc[8 rows][f4],
//           wave=(hh,chalf), lane=(jc16,colq4); 2x ds_read_b128 (conflict-free)
//           + 1 global f4 h read per s-iter; shfl-reduce over 16 jc at end.
// ---------------------------------------------------------------------------
__global__ __launch_bounds__(512, 8) void gat_attn_kernel(
    const float* __restrict__ adj, const float* __restrict__ attn,
    const float* __restrict__ hfeat, const float* __restrict__ srcv,
    const float* __restrict__ dstv,
    float* __restrict__ out, float* __restrict__ alpha)
{
    __shared__ float src_l[32];
    __shared__ float rs_l[32];
    __shared__ float al_l[4 * 64 * 12];   // [h][jj][r(8)+pad4], f4-aligned

    const int tid  = threadIdx.x;
    const int lane = tid & 63;
    const int w    = tid >> 6;               // 8 waves
    const int b    = blockIdx.x & 7;         // XCD-local batch
    const int i0   = (blockIdx.x >> 3) * 8;  // 128 i-tiles per batch

    float aE[4];
    #pragma unroll
    for (int h = 0; h < 4; ++h) aE[h] = attn[h * 65 + 64];

    if (tid < 32) src_l[tid] = srcv[(size_t)(b * N_ + i0) * 4 + tid];
    __syncthreads();

    // ---------------- Pass A: s = sum_j exp(leaky(e)), 1 row per wave ------
    const float* dstb = dstv + (size_t)b * N_ * 4;
    const float* arow = adj + ((size_t)(b * N_ + i0 + w)) * N_;
    {
        float sd[4];
        #pragma unroll
        for (int h = 0; h < 4; ++h) sd[h] = src_l[w * 4 + h];
        float s[4] = {0.f, 0.f, 0.f, 0.f};
        #pragma unroll
        for (int k = 0; k < 4; ++k) {
            f4 av4 = __builtin_nontemporal_load((const f4*)(arow + lane * 4 + k * 256));
            #pragma unroll
            for (int q = 0; q < 4; ++q) {
                float av = av4[q];
                if (av != 0.f) {
                    int j = lane * 4 + k * 256 + q;
                    f4 dv = *(const f4*)(dstb + j * 4);
                    #pragma unroll
                    for (int h = 0; h < 4; ++h) {
                        float e = fmaf(av, aE[h], sd[h] + dv[h]);
                        e = e >= 0.f ? e : NEG * e;
                        s[h] += __expf(e);
                    }
                }
            }
        }
        #pragma unroll
        for (int m = 1; m <= 32; m <<= 1) {
            #pragma unroll
            for (int h = 0; h < 4; ++h) s[h] += __shfl_xor(s[h], m);
        }
        if (lane == 0) {
            #pragma unroll
            for (int h = 0; h < 4; ++h)
                rs_l[w * 4 + h] = s[h] > 0.f ? 1.f / s[h] : 0.f;
        }
        // no barrier: rs_l[w] / src_l[w] are consumed by wave w itself below
    }

    // ---------------- Main loop over 16 j-tiles ----------------
    const int hh    = w >> 1;
    const int chalf = w & 1;
    const int jc    = lane & 15;
    const int colq  = lane >> 4;
    const int hcol  = hh * 32 + chalf * 16 + colq * 4;
    f4 acc[8];
    #pragma unroll
    for (int r = 0; r < 8; ++r) acc[r] = (f4)0.f;

    float* alrow = alpha + ((size_t)(b * N_ + i0 + w)) * N_ * 4;
    float av_cur = __builtin_nontemporal_load(arow + lane);
    float av_next = 0.f;

    for (int jt = 0; jt < 16; ++jt) {
        const int j0 = jt * 64;
        // ---- phase 1: alpha (1 task/thread: r = w, jj = lane) ----
        f4 al = (f4)0.f;
        if (av_cur != 0.f) {
            f4 dv  = *(const f4*)(dstb + (j0 + lane) * 4);
            f4 sdv = *(const f4*)&src_l[w * 4];
            f4 rsv = *(const f4*)&rs_l[w * 4];
            #pragma unroll
            for (int h = 0; h < 4; ++h) {
                float e = fmaf(av_cur, aE[h], sdv[h] + dv[h]);
                e = e >= 0.f ? e : NEG * e;
                al[h] = __expf(e) * rsv[h];
            }
        }
        #pragma unroll
        for (int h = 0; h < 4; ++h)
            al_l[h * 768 + lane * 12 + w] = al[h];
        __builtin_nontemporal_store(al, (f4*)(alrow + (j0 + lane) * 4));
        __syncthreads();
        // ---- phase 2: PV ----
        if (jt < 15) av_next = __builtin_nontemporal_load(arow + j0 + 64 + lane);
        #pragma unroll
        for (int s = 0; s < 4; ++s) {
            int jj = s * 16 + jc;
            const float* ab = &al_l[hh * 768 + jj * 12];
            f4 avA = *(const f4*)ab;        // rows 0..3
            f4 avB = *(const f4*)(ab + 4);  // rows 4..7
            f4 hv = *(const f4*)(hfeat + (size_t)(b * N_ + j0 + jj) * 128 + hcol);
            acc[0] += avA.x * hv; acc[1] += avA.y * hv;
            acc[2] += avA.z * hv; acc[3] += avA.w * hv;
            acc[4] += avB.x * hv; acc[5] += avB.y * hv;
            acc[6] += avB.z * hv; acc[7] += avB.w * hv;
        }
        __syncthreads();
        av_cur = av_next;
    }

    // reduce over the 16 jc lanes (lane bits 0..3)
    #pragma unroll
    for (int m = 1; m <= 8; m <<= 1) {
        #pragma unroll
        for (int r = 0; r < 8; ++r) {
            acc[r].x += __shfl_xor(acc[r].x, m);
            acc[r].y += __shfl_xor(acc[r].y, m);
            acc[r].z += __shfl_xor(acc[r].z, m);
            acc[r].w += __shfl_xor(acc[r].w, m);
        }
    }
    #pragma unroll
    for (int r = 0; r < 8; ++r) {
        if (jc == r)
            *(f4*)(out + (size_t)(b * N_ + i0 + r) * 128 + hcol) = acc[r];
    }
}

extern "C" void kernel_launch(void* const* d_in, const int* in_sizes, int n_in,
                              void* d_out, int out_size, void* d_ws, size_t ws_size,
                              hipStream_t stream) {
    const float* x    = (const float*)d_in[0];
    const float* adj  = (const float*)d_in[1];
    const float* Ww   = (const float*)d_in[2];
    const float* attn = (const float*)d_in[3];

    float* out   = (float*)d_out;                    // [8,1024,128]
    float* alpha = out + (size_t)B_ * N_ * 128;      // [8,1024,1024,4]

    float* hfeat = (float*)d_ws;                     // 4 MB
    float* srcv  = hfeat + (size_t)B_ * N_ * 128;
    float* dstv  = srcv + (size_t)B_ * N_ * 4;

    gat_h_kernel<<<512, 256, 0, stream>>>(x, Ww, attn, hfeat, srcv, dstv);
    gat_attn_kernel<<<1024, 512, 0, stream>>>(adj, attn, hfeat, srcv, dstv, out, alpha);
}